// Round 4
// baseline (826.304 us; speedup 1.0000x reference)
//
#include <hip/hip_runtime.h>
#include <math.h>

#define G 8
#define T 4096
#define H 1024
#define E 32
#define C 64
#define NTOK (G*T)                     // 32768 tokens
#define COMBINE_SZ ((size_t)G*T*E*C)   // 67108864 floats
#define COMBINE_F4 16777216u           // combine size in float4

// ---------------------------------------------------------------------------
// Fully fused kernel: 512 blocks x 256 threads.
//  Producer role (ALL blocks): GEMM for 64 tokens + fused zeroing of a slice
//   of its OWN group's output region + softmax + z-partial + transposed probs;
//   then __syncthreads (drains stores) + __threadfence (L2 writeback) +
//   release-increment of cnt[group].
//  Consumer role (ODD blocks, ge = blk>>1, same group as its chunk): spin on
//   cnt[g]==64 (acquire), then top-64 rounds + winner scatter. Winner lines
//   were zeroed by group-g producers, whose stores are flushed before their
//   increments -> no store/store hazard. Top-k rounds overlap the global
//   HBM write drain of other groups' zeros.
//  Block 1 additionally reduces the 512 z-loss partials after all groups done.
// Deadlock-free at any residency: even blocks never spin and retire, freeing
// slots for any not-yet-scheduled producers.
// NOTE: GEMM/softmax/top-k math is verbatim from R2/R3 (absmax 0.0) — do not
// perturb accumulation order.
// ---------------------------------------------------------------------------
__global__ __launch_bounds__(256) void k_fused(
    const float* __restrict__ x, const float* __restrict__ W,
    const float* __restrict__ bias, float* __restrict__ probs_t,
    float* __restrict__ out, float* __restrict__ zpart,
    unsigned* __restrict__ cnt)
{
    __shared__ float lt[64][33];   // [token][expert], +1 pad
    __shared__ unsigned long long wmax[4];
    __shared__ unsigned long long gkls;

    const int tid  = threadIdx.x;
    const int lane = tid & 63;
    const int wv   = __builtin_amdgcn_readfirstlane(tid >> 6);
    const int blk  = blockIdx.x;
    const int g    = blk >> 6;          // group of this token chunk
    const int q    = blk & 63;          // chunk-within-group
    const int tok  = blk * 64 + lane;
    const float* __restrict__ xr = x + (size_t)tok * H;
    const float* __restrict__ Wg = W + wv * 8;

    float4* __restrict__ zq4 = (float4*)out;
    const float4 zero4 = make_float4(0.f, 0.f, 0.f, 0.f);

    // ---------------- producer phase ----------------
    float acc[8] = {0,0,0,0,0,0,0,0};
    for (int h = 0; h < H; h += 4) {
        const float4 xv = *(const float4*)(xr + h);
        {   // fused zeroing of this block's slice of group g's output region:
            // steps 0..127 -> combine part, 128..255 -> dispatch part
            const int i  = h >> 2;
            const unsigned half = (unsigned)(i >> 7);
            const unsigned ii   = (unsigned)(i & 127);
            const size_t zidx = (size_t)half * COMBINE_F4
                              + (size_t)g * 2097152u + (unsigned)q * 32768u
                              + ii * 256u + (unsigned)tid;
            zq4[zidx] = zero4;
        }
        #pragma unroll
        for (int j = 0; j < 4; ++j) {
            const float4 w0 = *(const float4*)(Wg + (h + j) * E);
            const float4 w1 = *(const float4*)(Wg + (h + j) * E + 4);
            const float xs = (j == 0) ? xv.x : (j == 1) ? xv.y : (j == 2) ? xv.z : xv.w;
            acc[0] = fmaf(xs, w0.x, acc[0]);
            acc[1] = fmaf(xs, w0.y, acc[1]);
            acc[2] = fmaf(xs, w0.z, acc[2]);
            acc[3] = fmaf(xs, w0.w, acc[3]);
            acc[4] = fmaf(xs, w1.x, acc[4]);
            acc[5] = fmaf(xs, w1.y, acc[5]);
            acc[6] = fmaf(xs, w1.z, acc[6]);
            acc[7] = fmaf(xs, w1.w, acc[7]);
        }
    }
    #pragma unroll
    for (int e = 0; e < 8; ++e) acc[e] += bias[wv * 8 + e];
    #pragma unroll
    for (int e = 0; e < 8; ++e) lt[lane][wv * 8 + e] = acc[e];
    __syncthreads();

    // softmax + z-loss partial: wave 0, one token per lane
    if (tid < 64) {
        float v[E];
        float m = -1e30f;
        #pragma unroll
        for (int e = 0; e < E; ++e) { v[e] = lt[tid][e]; m = fmaxf(m, v[e]); }
        float s = 0.f;
        #pragma unroll
        for (int e = 0; e < E; ++e) { v[e] = expf(v[e] - m); s += v[e]; }
        const float inv = 1.f / s;
        #pragma unroll
        for (int e = 0; e < E; ++e) lt[tid][e] = v[e] * inv;
        const float lz = m + logf(s);
        float zsq = lz * lz;
        #pragma unroll
        for (int off = 32; off; off >>= 1) zsq += __shfl_down(zsq, off, 64);
        if (tid == 0) zpart[blk] = zsq * (1.0f / (float)NTOK);
    }
    __syncthreads();

    // store probs transposed: probs_t[(g*E+e)*T + t]
    {
        const int base = blk * 64;
        const int tb   = base & (T - 1);
        #pragma unroll
        for (int j = 0; j < 8; ++j) {
            const int e = wv * 8 + j;
            probs_t[((size_t)(g * E + e)) * T + tb + lane] = lt[lane][e];
        }
    }
    // drain all of this block's stores (syncthreads implies vmcnt(0) per wave),
    // write back L2 so other XCDs see probs + zeros, then signal.
    __syncthreads();
    if (tid == 0) {
        __threadfence();
        __hip_atomic_fetch_add(&cnt[g], 1u, __ATOMIC_RELEASE, __HIP_MEMORY_SCOPE_AGENT);
    }

    // ---------------- consumer phase (odd blocks) ----------------
    if (blk & 1) {
        const int ge = blk >> 1;         // g2 == g by construction
        const int e  = ge & 31;
        const float* __restrict__ col = probs_t + (size_t)ge * T;

        if (tid == 0) {
            while (__hip_atomic_load(&cnt[g], __ATOMIC_ACQUIRE,
                                     __HIP_MEMORY_SCOPE_AGENT) < 64u)
                __builtin_amdgcn_s_sleep(8);
        }
        __syncthreads();
        __threadfence();   // acquire: invalidate stale L1/L2 before probs reads

        float vals[16];
        unsigned long long keys[16];
        #pragma unroll
        for (int j = 0; j < 16; ++j) {
            const int t = j * 256 + tid;
            const float p = col[t];
            unsigned u = __float_as_uint(p);
            u = (u & 0x80000000u) ? ~u : (u | 0x80000000u);
            keys[j] = ((unsigned long long)u << 32) | (unsigned)(4095 - t);
            vals[j] = p;
        }

        for (int c = 0; c < C; ++c) {
            unsigned long long kmax = 0ull;
            #pragma unroll
            for (int j = 0; j < 16; ++j) kmax = (keys[j] > kmax) ? keys[j] : kmax;
            #pragma unroll
            for (int off = 32; off; off >>= 1) {
                const unsigned long long o = __shfl_xor(kmax, off, 64);
                kmax = (o > kmax) ? o : kmax;
            }
            if ((tid & 63) == 0) wmax[tid >> 6] = kmax;
            __syncthreads();
            if (tid == 0) {
                unsigned long long m = wmax[0];
                #pragma unroll
                for (int w = 1; w < 4; ++w) m = (wmax[w] > m) ? wmax[w] : m;
                gkls = m;
            }
            __syncthreads();
            const unsigned long long gkey = gkls;
            #pragma unroll
            for (int j = 0; j < 16; ++j) {
                if (keys[j] == gkey) {   // unique winner
                    const int t = 4095 - (int)(gkey & 0xFFFFFFFFu);
                    const size_t idx = ((((size_t)g * T + t) * E + e) * C + c);
                    out[idx] = vals[j];                 // combine = gate
                    out[idx + COMBINE_SZ] = 1.0f;       // dispatch mask
                    keys[j] = 0ull;
                }
            }
        }
    }

    // ---------------- z-loss reduction (block 1, after its top-k) ----------
    if (blk == 1) {
        if (tid == 0) {
            #pragma unroll
            for (int j = 0; j < G; ++j) {
                while (__hip_atomic_load(&cnt[j], __ATOMIC_ACQUIRE,
                                         __HIP_MEMORY_SCOPE_AGENT) < 64u)
                    __builtin_amdgcn_s_sleep(8);
            }
        }
        __syncthreads();
        __threadfence();
        if (tid < 64) {
            float s = 0.f;
            #pragma unroll
            for (int j = 0; j < 8; ++j) s += zpart[tid * 8 + j];
            #pragma unroll
            for (int off = 32; off; off >>= 1) s += __shfl_down(s, off, 64);
            if (tid == 0) out[2 * COMBINE_SZ] = s;
        }
    }
}

// ---------------------------------------------------------------------------
extern "C" void kernel_launch(void* const* d_in, const int* in_sizes, int n_in,
                              void* d_out, int out_size, void* d_ws, size_t ws_size,
                              hipStream_t stream) {
    const float* x = (const float*)d_in[0];   // [G,T,H]
    const float* W = (const float*)d_in[1];   // [H,E]
    const float* b = (const float*)d_in[2];   // [E]
    float* out     = (float*)d_out;           // combine | dispatch | z_loss
    float* probs_t = (float*)d_ws;            // [G*E, T] = 4 MB
    float* zpart   = (float*)d_ws + (size_t)G * E * T;   // 512 floats
    unsigned* cnt  = (unsigned*)((float*)d_ws + (size_t)G * E * T + 512);  // 8 u32

    // counters must start at 0 every launch (ws is poisoned to 0xAA)
    hipMemsetAsync(cnt, 0, G * sizeof(unsigned), stream);
    k_fused<<<512, 256, 0, stream>>>(x, W, b, probs_t, out, zpart, cnt);
}

// Round 6
// 699.758 us; speedup vs baseline: 1.1808x; 1.1808x over previous
//
#include <hip/hip_runtime.h>
#include <math.h>

#define G 8
#define T 4096
#define H 1024
#define E 32
#define C 64
#define NTOK (G*T)                     // 32768 tokens
#define COMBINE_SZ ((size_t)G*T*E*C)   // 67108864 floats
#define KC 128                         // h-chunk size

// ---------------------------------------------------------------------------
// Kernel 1: router logits GEMM (fp32 vector) + softmax + z-loss + transposed
// probs store.  Grid: NTOK/64 = 512 blocks x 256 threads.  Block = 64 tokens.
// Wave w (0..3) computes experts [8w, 8w+8) for all 64 tokens (lane = token).
//
// R5 fix (R4 diagnosis: GEMM latency-bound, VALUBusy 7%):
//  - W chunk (128 h x 32 e = 16 KB) staged in LDS via fully-contiguous
//    coalesced float4 loads; compute reads are wave-uniform ds_read_b128
//    broadcasts (conflict-free).  Kills the s_load scalar-cache-miss chain.
//  - x tile (64 tok x 128 h) staged in LDS via coalesced loads (64 lanes =
//    two full 512 B row segments per instr); compute reads from padded rows
//    (stride 132 -> 8-way conflict, ~2.9x on that op only, minor).
//  - Accumulation order (h ascending, fmaf, per-expert) is VERBATIM from R2
//    (absmax 0.0) — do not perturb.
// ---------------------------------------------------------------------------
__global__ __launch_bounds__(256) void k_router(
    const float* __restrict__ x, const float* __restrict__ W,
    const float* __restrict__ bias, float* __restrict__ probs_t,
    float* __restrict__ z_out)
{
    __shared__ float xs[64][132];   // 33.8 KB, +4 pad keeps 16B align, breaks bank stride
    __shared__ float ws[KC][32];    // 16 KB
    __shared__ float lt[64][33];    // 8.4 KB   (total 58.6 KB)

    const int tid  = threadIdx.x;
    const int lane = tid & 63;
    const int wv   = __builtin_amdgcn_readfirstlane(tid >> 6);
    const int blk  = blockIdx.x;

    float acc[8] = {0,0,0,0,0,0,0,0};

    for (int ch = 0; ch < H / KC; ++ch) {
        const int h0 = ch * KC;

        // --- cooperative W chunk load: contiguous 16 KB, perfectly coalesced
        {
            const float4* __restrict__ src = (const float4*)(W + (size_t)h0 * E);
            float4* __restrict__ dst = (float4*)ws;
            #pragma unroll
            for (int k = 0; k < 4; ++k) dst[k * 256 + tid] = src[k * 256 + tid];
        }
        // --- cooperative x tile load: 64 tokens x 128 h; flat float4 idx
        //     f: tok = f>>5, h4 = f&31 -> 64 consecutive lanes cover 2 full
        //     512 B row segments (coalesced)
        #pragma unroll
        for (int k = 0; k < 8; ++k) {
            const int f   = k * 256 + tid;
            const int tok = f >> 5;
            const int h4  = f & 31;
            const float4 v = *(const float4*)(x + ((size_t)(blk * 64 + tok)) * H + h0 + h4 * 4);
            *(float4*)(&xs[tok][h4 * 4]) = v;
        }
        __syncthreads();

        // --- compute: lane = token, wave = expert-group of 8
        for (int hh = 0; hh < KC; hh += 4) {
            const float4 xv = *(const float4*)(&xs[lane][hh]);
            #pragma unroll
            for (int j = 0; j < 4; ++j) {
                const float4 w0 = *(const float4*)(&ws[hh + j][wv * 8]);
                const float4 w1 = *(const float4*)(&ws[hh + j][wv * 8 + 4]);
                const float xsc = (j == 0) ? xv.x : (j == 1) ? xv.y : (j == 2) ? xv.z : xv.w;
                acc[0] = fmaf(xsc, w0.x, acc[0]);
                acc[1] = fmaf(xsc, w0.y, acc[1]);
                acc[2] = fmaf(xsc, w0.z, acc[2]);
                acc[3] = fmaf(xsc, w0.w, acc[3]);
                acc[4] = fmaf(xsc, w1.x, acc[4]);
                acc[5] = fmaf(xsc, w1.y, acc[5]);
                acc[6] = fmaf(xsc, w1.z, acc[6]);
                acc[7] = fmaf(xsc, w1.w, acc[7]);
            }
        }
        __syncthreads();
    }

    #pragma unroll
    for (int e = 0; e < 8; ++e) acc[e] += bias[wv * 8 + e];
    #pragma unroll
    for (int e = 0; e < 8; ++e) lt[lane][wv * 8 + e] = acc[e];
    __syncthreads();

    // softmax + z-loss: wave 0, one token per lane (verbatim R2)
    if (tid < 64) {
        float v[E];
        float m = -1e30f;
        #pragma unroll
        for (int e = 0; e < E; ++e) { v[e] = lt[tid][e]; m = fmaxf(m, v[e]); }
        float s = 0.f;
        #pragma unroll
        for (int e = 0; e < E; ++e) { v[e] = expf(v[e] - m); s += v[e]; }
        const float inv = 1.f / s;
        #pragma unroll
        for (int e = 0; e < E; ++e) lt[tid][e] = v[e] * inv;
        const float lz = m + logf(s);
        float zsq = lz * lz;
        #pragma unroll
        for (int off = 32; off; off >>= 1) zsq += __shfl_down(zsq, off, 64);
        if (tid == 0) atomicAdd(z_out, zsq * (1.0f / (float)NTOK));
    }
    __syncthreads();

    // store probs transposed: probs_t[(g*E+e)*T + t]
    const int base = blk * 64;
    const int g    = base >> 12;
    const int tb   = base & (T - 1);
    #pragma unroll
    for (int j = 0; j < 8; ++j) {
        const int e = wv * 8 + j;
        probs_t[((size_t)(g * E + e)) * T + tb + lane] = lt[lane][e];
    }
}

// ---------------------------------------------------------------------------
// Kernel 2: per-(g,e) top-64 with exact jax.lax.top_k tie semantics
// (descending, ties -> lower index); scatter into zeroed combine/dispatch.
// Verbatim R2 (absmax 0.0).
// ---------------------------------------------------------------------------
__global__ __launch_bounds__(256) void k_topk(
    const float* __restrict__ probs_t, float* __restrict__ out)
{
    const int ge  = blockIdx.x;          // g*E + e
    const int g   = ge >> 5;
    const int e   = ge & 31;
    const int tid = threadIdx.x;
    const float* __restrict__ col = probs_t + (size_t)ge * T;

    float vals[16];
    unsigned long long keys[16];
    #pragma unroll
    for (int j = 0; j < 16; ++j) {
        const int t = j * 256 + tid;
        const float p = col[t];
        unsigned u = __float_as_uint(p);
        u = (u & 0x80000000u) ? ~u : (u | 0x80000000u);
        keys[j] = ((unsigned long long)u << 32) | (unsigned)(4095 - t);
        vals[j] = p;
    }

    __shared__ unsigned long long wmax[4];
    __shared__ unsigned long long gk;

    for (int c = 0; c < C; ++c) {
        unsigned long long kmax = 0ull;
        #pragma unroll
        for (int j = 0; j < 16; ++j) kmax = (keys[j] > kmax) ? keys[j] : kmax;
        #pragma unroll
        for (int off = 32; off; off >>= 1) {
            const unsigned long long o = __shfl_xor(kmax, off, 64);
            kmax = (o > kmax) ? o : kmax;
        }
        if ((tid & 63) == 0) wmax[tid >> 6] = kmax;
        __syncthreads();
        if (tid == 0) {
            unsigned long long m = wmax[0];
            #pragma unroll
            for (int w = 1; w < 4; ++w) m = (wmax[w] > m) ? wmax[w] : m;
            gk = m;
        }
        __syncthreads();
        const unsigned long long gkey = gk;
        #pragma unroll
        for (int j = 0; j < 16; ++j) {
            if (keys[j] == gkey) {   // unique winner
                const int t = 4095 - (int)(gkey & 0xFFFFFFFFu);
                const size_t idx = ((((size_t)g * T + t) * E + e) * C + c);
                out[idx] = vals[j];                 // combine = gate
                out[idx + COMBINE_SZ] = 1.0f;       // dispatch mask
                keys[j] = 0ull;
            }
        }
    }
}

// ---------------------------------------------------------------------------
extern "C" void kernel_launch(void* const* d_in, const int* in_sizes, int n_in,
                              void* d_out, int out_size, void* d_ws, size_t ws_size,
                              hipStream_t stream) {
    const float* x = (const float*)d_in[0];   // [G,T,H]
    const float* W = (const float*)d_in[1];   // [H,E]
    const float* b = (const float*)d_in[2];   // [E]
    float* out     = (float*)d_out;           // combine | dispatch | z_loss
    float* probs_t = (float*)d_ws;            // [G*E, T] = 4 MB scratch

    // outputs are one-hot-sparse; zero everything (incl. z_loss slot), then scatter
    hipMemsetAsync(d_out, 0, (size_t)out_size * sizeof(float), stream);

    k_router<<<NTOK / 64, 256, 0, stream>>>(x, W, b, probs_t, out + 2 * COMBINE_SZ);
    k_topk<<<G * E, 256, 0, stream>>>(probs_t, out);
}

// Round 9
// 693.008 us; speedup vs baseline: 1.1923x; 1.0097x over previous
//
#include <hip/hip_runtime.h>
#include <math.h>

#define G 8
#define T 4096
#define H 1024
#define E 32
#define C 64
#define NTOK (G*T)                     // 32768 tokens
#define COMBINE_SZ ((size_t)G*T*E*C)   // 67108864 floats
#define KC 64                          // h-chunk size
#define TBLK 128                       // tokens per block (2 per lane)

// ---------------------------------------------------------------------------
// Kernel 1: router logits GEMM (fp32 vector) + softmax + z-loss + transposed
// probs store.  Grid: NTOK/128 = 256 blocks x 256 threads.
// Wave w (0..3) computes experts [8w,8w+8) for all 128 tokens; lane l holds
// tokens {l, 64+l} (2 per lane, 16 accumulators).
//
// R7 fix (R6 analysis: k_router ~115us, LDS-pipe bound on W broadcast reads —
// 2048 ds_read_b128/wave x 2048 waves): register-block 2 tokens/lane halves
// the wave count -> halves total W-broadcast instructions. FMA chain per
// (token,expert) remains h-ascending fmaf — VERBATIM R2 math (absmax 0.0).
// ---------------------------------------------------------------------------
__global__ __launch_bounds__(256) void k_router(
    const float* __restrict__ x, const float* __restrict__ W,
    const float* __restrict__ bias, float* __restrict__ probs_t,
    float* __restrict__ z_out)
{
    __shared__ float xs[TBLK][68];  // 34.8 KB; row stride 68 floats (16B-aligned)
    __shared__ float ws2[KC][32];   // 8 KB
    __shared__ float lt[TBLK][33];  // 16.9 KB  (total 59.9 KB)

    const int tid  = threadIdx.x;
    const int lane = tid & 63;
    const int wv   = __builtin_amdgcn_readfirstlane(tid >> 6);
    const int blk  = blockIdx.x;

    float acc0[8] = {0,0,0,0,0,0,0,0};   // token = blk*128 + lane
    float acc1[8] = {0,0,0,0,0,0,0,0};   // token = blk*128 + 64 + lane

    for (int ch = 0; ch < H / KC; ++ch) {
        const int h0 = ch * KC;

        // --- W chunk: 64 h x 32 e = 8 KB, contiguous, coalesced
        {
            const float4* __restrict__ src = (const float4*)(W + (size_t)h0 * E);
            float4* __restrict__ dst = (float4*)ws2;
            dst[tid]       = src[tid];
            dst[tid + 256] = src[tid + 256];
        }
        // --- x tile: 128 tok x 64 h; f -> tok=f>>4, h4=f&15 (16 lanes cover a
        //     256 B contiguous row segment; 4 segments per wave-instr)
        #pragma unroll
        for (int k = 0; k < 8; ++k) {
            const int f   = k * 256 + tid;
            const int tok = f >> 4;
            const int h4  = f & 15;
            const float4 v = *(const float4*)(x + (size_t)(blk * TBLK + tok) * H + h0 + h4 * 4);
            *(float4*)(&xs[tok][h4 * 4]) = v;
        }
        __syncthreads();

        // --- compute: 2 tokens/lane x 8 experts
        for (int hh = 0; hh < KC; hh += 4) {
            const float4 xa = *(const float4*)(&xs[lane][hh]);
            const float4 xb = *(const float4*)(&xs[64 + lane][hh]);
            #pragma unroll
            for (int j = 0; j < 4; ++j) {
                const float4 w0 = *(const float4*)(&ws2[hh + j][wv * 8]);
                const float4 w1 = *(const float4*)(&ws2[hh + j][wv * 8 + 4]);
                const float a_ = (j == 0) ? xa.x : (j == 1) ? xa.y : (j == 2) ? xa.z : xa.w;
                const float b_ = (j == 0) ? xb.x : (j == 1) ? xb.y : (j == 2) ? xb.z : xb.w;
                acc0[0] = fmaf(a_, w0.x, acc0[0]);  acc1[0] = fmaf(b_, w0.x, acc1[0]);
                acc0[1] = fmaf(a_, w0.y, acc0[1]);  acc1[1] = fmaf(b_, w0.y, acc1[1]);
                acc0[2] = fmaf(a_, w0.z, acc0[2]);  acc1[2] = fmaf(b_, w0.z, acc1[2]);
                acc0[3] = fmaf(a_, w0.w, acc0[3]);  acc1[3] = fmaf(b_, w0.w, acc1[3]);
                acc0[4] = fmaf(a_, w1.x, acc0[4]);  acc1[4] = fmaf(b_, w1.x, acc1[4]);
                acc0[5] = fmaf(a_, w1.y, acc0[5]);  acc1[5] = fmaf(b_, w1.y, acc1[5]);
                acc0[6] = fmaf(a_, w1.z, acc0[6]);  acc1[6] = fmaf(b_, w1.z, acc1[6]);
                acc0[7] = fmaf(a_, w1.w, acc0[7]);  acc1[7] = fmaf(b_, w1.w, acc1[7]);
            }
        }
        __syncthreads();
    }

    #pragma unroll
    for (int e = 0; e < 8; ++e) {
        const float be = bias[wv * 8 + e];
        lt[lane][wv * 8 + e]      = acc0[e] + be;
        lt[64 + lane][wv * 8 + e] = acc1[e] + be;
    }
    __syncthreads();

    // softmax + z-loss: waves 0,1 — one token per lane (math verbatim R2)
    if (tid < TBLK) {
        float v[E];
        float m = -1e30f;
        #pragma unroll
        for (int e = 0; e < E; ++e) { v[e] = lt[tid][e]; m = fmaxf(m, v[e]); }
        float s = 0.f;
        #pragma unroll
        for (int e = 0; e < E; ++e) { v[e] = expf(v[e] - m); s += v[e]; }
        const float inv = 1.f / s;
        #pragma unroll
        for (int e = 0; e < E; ++e) lt[tid][e] = v[e] * inv;
        const float lz = m + logf(s);
        float zsq = lz * lz;
        #pragma unroll
        for (int off = 32; off; off >>= 1) zsq += __shfl_down(zsq, off, 64);
        // same 64-token partial groups + same shfl tree as R2/R6; 512 atomics total
        if ((tid & 63) == 0) atomicAdd(z_out, zsq * (1.0f / (float)NTOK));
    }
    __syncthreads();

    // store probs transposed: probs_t[(g*E+e)*T + t], 128 tokens per block
    const int g  = blk >> 5;           // 32 blocks per group
    const int tb = (blk & 31) * TBLK;
    #pragma unroll
    for (int j = 0; j < 8; ++j) {
        const int e = wv * 8 + j;
        float* __restrict__ col = probs_t + ((size_t)(g * E + e)) * T + tb;
        col[lane]      = lt[lane][e];
        col[64 + lane] = lt[64 + lane][e];
    }
}

// ---------------------------------------------------------------------------
// Kernel 2: per-(g,e) top-64 with exact jax.lax.top_k tie semantics
// (descending, ties -> lower index); scatter into zeroed combine/dispatch.
// Verbatim R2 (absmax 0.0).
// ---------------------------------------------------------------------------
__global__ __launch_bounds__(256) void k_topk(
    const float* __restrict__ probs_t, float* __restrict__ out)
{
    const int ge  = blockIdx.x;          // g*E + e
    const int g   = ge >> 5;
    const int e   = ge & 31;
    const int tid = threadIdx.x;
    const float* __restrict__ col = probs_t + (size_t)ge * T;

    float vals[16];
    unsigned long long keys[16];
    #pragma unroll
    for (int j = 0; j < 16; ++j) {
        const int t = j * 256 + tid;
        const float p = col[t];
        unsigned u = __float_as_uint(p);
        u = (u & 0x80000000u) ? ~u : (u | 0x80000000u);
        keys[j] = ((unsigned long long)u << 32) | (unsigned)(4095 - t);
        vals[j] = p;
    }

    __shared__ unsigned long long wmax[4];
    __shared__ unsigned long long gk;

    for (int c = 0; c < C; ++c) {
        unsigned long long kmax = 0ull;
        #pragma unroll
        for (int j = 0; j < 16; ++j) kmax = (keys[j] > kmax) ? keys[j] : kmax;
        #pragma unroll
        for (int off = 32; off; off >>= 1) {
            const unsigned long long o = __shfl_xor(kmax, off, 64);
            kmax = (o > kmax) ? o : kmax;
        }
        if ((tid & 63) == 0) wmax[tid >> 6] = kmax;
        __syncthreads();
        if (tid == 0) {
            unsigned long long m = wmax[0];
            #pragma unroll
            for (int w = 1; w < 4; ++w) m = (wmax[w] > m) ? wmax[w] : m;
            gk = m;
        }
        __syncthreads();
        const unsigned long long gkey = gk;
        #pragma unroll
        for (int j = 0; j < 16; ++j) {
            if (keys[j] == gkey) {   // unique winner
                const int t = 4095 - (int)(gkey & 0xFFFFFFFFu);
                const size_t idx = ((((size_t)g * T + t) * E + e) * C + c);
                out[idx] = vals[j];                 // combine = gate
                out[idx + COMBINE_SZ] = 1.0f;       // dispatch mask
                keys[j] = 0ull;
            }
        }
    }
}

// ---------------------------------------------------------------------------
extern "C" void kernel_launch(void* const* d_in, const int* in_sizes, int n_in,
                              void* d_out, int out_size, void* d_ws, size_t ws_size,
                              hipStream_t stream) {
    const float* x = (const float*)d_in[0];   // [G,T,H]
    const float* W = (const float*)d_in[1];   // [H,E]
    const float* b = (const float*)d_in[2];   // [E]
    float* out     = (float*)d_out;           // combine | dispatch | z_loss
    float* probs_t = (float*)d_ws;            // [G*E, T] = 4 MB scratch

    // outputs are one-hot-sparse; zero everything (incl. z_loss slot), then scatter
    hipMemsetAsync(d_out, 0, (size_t)out_size * sizeof(float), stream);

    k_router<<<NTOK / TBLK, 256, 0, stream>>>(x, W, b, probs_t, out + 2 * COMBINE_SZ);
    k_topk<<<G * E, 256, 0, stream>>>(probs_t, out);
}